// Round 18
// baseline (247.545 us; speedup 1.0000x reference)
//
#include <hip/hip_runtime.h>
#include <hip/hip_bf16.h>

#define IN_DIM 128
#define HC 128   // H*C
#define NH 4     // heads
#define CH 32    // channels per head
#define EDGE_DIM 32
#define CAP 48   // slots per dst; degree ~ Poisson(16), P(deg>48) ~ 1e-10

typedef short s8v __attribute__((ext_vector_type(8)));   // 8 bf16 (4 VGPR)
typedef float f4v __attribute__((ext_vector_type(4)));   // mfma acc

// ---------------------------------------------------------------------------
__device__ __forceinline__ unsigned pack_bf16(float a, float b) {
    unsigned ua = __float_as_uint(a), ub = __float_as_uint(b);
    ua += 0x7fffu + ((ua >> 16) & 1u);
    ub += 0x7fffu + ((ub >> 16) & 1u);
    return (ua >> 16) | (ub & 0xffff0000u);
}
__device__ __forceinline__ unsigned short bf16_1(float a) {
    unsigned ua = __float_as_uint(a);
    ua += 0x7fffu + ((ua >> 16) & 1u);
    return (unsigned short)(ua >> 16);
}

// ---------------------------------------------------------------------------
// K0: fused tiny prep: blocks 0..63 -> Wt[n][k]=bf16(W[k][n]); block 64 -> v_edge
// ---------------------------------------------------------------------------
__global__ __launch_bounds__(256) void k_vp(
    const float* __restrict__ W_edge, const float* __restrict__ att_edge,
    float* __restrict__ v_edge, const float* __restrict__ W,
    unsigned short* __restrict__ Wt)
{
    int b = blockIdx.x, t = threadIdx.x;
    if (b == 64) {
        if (t < 128) {
            int h = t >> 5, k = t & 31;
            float s = 0.f;
            #pragma unroll
            for (int c = 0; c < CH; ++c)
                s += W_edge[k * HC + h * CH + c] * att_edge[h * CH + c];
            v_edge[h * EDGE_DIM + k] = s;
        }
    } else {
        int id = b * 256 + t;
        int n = id >> 7, k = id & 127;
        Wt[n * 128 + k] = bf16_1(W[k * 128 + n]);
    }
}

// ---------------------------------------------------------------------------
// K1 (fused single pass): blocks [0,nbEdge): edge stream -> a_edge dot +
// DIRECT slot scatter. Atomic issued EARLY (before the dot) so its cross-XCD
// round trip hides under the 8x float4 loads + dot.
// blocks [nbEdge,...): x = A@W via bf16 MFMA.
// ---------------------------------------------------------------------------
__global__ __launch_bounds__(256) void k_phase1(
    const float* __restrict__ edge_attr, const int* __restrict__ ei,
    const float* __restrict__ v_edge, int* __restrict__ cnt,
    int4* __restrict__ slots,
    const float* __restrict__ A, const unsigned short* __restrict__ Wt,
    unsigned short* __restrict__ xb16, int N, int E, int nbEdge)
{
    __shared__ unsigned Al[64 * 64];   // gemm A tile (16 KB)
    __shared__ float vl[HC];           // edge path v_edge

    int t = threadIdx.x;

    if (blockIdx.x < nbEdge) {
        if (t < HC) vl[t] = v_edge[t];
        __syncthreads();
        int e = blockIdx.x * 256 + t;
        if (e >= E) return;

        // issue index loads + atomic FIRST; latency hides under the dot
        int src = ei[e], dst = ei[E + e];
        int pos = atomicAdd(&cnt[dst], 1);

        const float4* ea4 = (const float4*)edge_attr + (size_t)e * 8;
        float ae[4] = {0.f, 0.f, 0.f, 0.f};
        #pragma unroll
        for (int j = 0; j < 8; ++j) {
            float4 v = ea4[j];
            #pragma unroll
            for (int h = 0; h < 4; ++h) {
                const float* vh = &vl[h * 32 + j * 4];
                ae[h] += v.x * vh[0] + v.y * vh[1] + v.z * vh[2] + v.w * vh[3];
            }
        }
        if (pos < CAP) {
            int4 pk;
            pk.x = src;
            pk.y = (int)pack_bf16(ae[0], ae[1]);
            pk.z = (int)pack_bf16(ae[2], ae[3]);
            pk.w = 0;
            slots[(size_t)dst * CAP + pos] = pk;
        }
    } else {
        int node0 = (blockIdx.x - nbEdge) * 64;
        const float4* A4 = (const float4*)A;
        #pragma unroll
        for (int it = 0; it < 8; ++it) {
            int id = it * 256 + t;
            int row = id >> 5, c = id & 31;
            float4 v = {0.f, 0.f, 0.f, 0.f};
            if (node0 + row < N) v = A4[(size_t)(node0 + row) * 32 + c];
            unsigned u0 = pack_bf16(v.x, v.y);
            unsigned u1 = pack_bf16(v.z, v.w);
            int k2 = 2 * c;
            int slot = k2 >> 2;
            int idx = ((slot ^ (row & 15)) << 2) | (k2 & 3);
            Al[row * 64 + idx]     = u0;
            Al[row * 64 + idx + 1] = u1;
        }
        __syncthreads();

        int l = t & 63;
        int w = t >> 6;
        int lrow = l & 15;
        int lk   = l >> 4;

        s8v afr[4];
        #pragma unroll
        for (int kb = 0; kb < 4; ++kb) {
            int slot = kb * 4 + lk;
            const unsigned* p = &Al[(w * 16 + lrow) * 64 + ((slot ^ lrow) << 2)];
            afr[kb] = *(const s8v*)p;
        }

        #pragma unroll
        for (int ct = 0; ct < 8; ++ct) {
            int col = ct * 16 + lrow;
            f4v acc = {0.f, 0.f, 0.f, 0.f};
            #pragma unroll
            for (int kb = 0; kb < 4; ++kb) {
                s8v bfr = *(const s8v*)&Wt[col * 128 + kb * 32 + lk * 8];
                acc = __builtin_amdgcn_mfma_f32_16x16x32_bf16(afr[kb], bfr, acc, 0, 0, 0);
            }
            #pragma unroll
            for (int r = 0; r < 4; ++r) {
                int node = node0 + w * 16 + lk * 4 + r;
                if (node < N) xb16[(size_t)node * 128 + col] = bf16_1(acc[r]);
            }
        }
    }
}

// ---------------------------------------------------------------------------
// K2: a_src/a_dst from bf16 x. 16 lanes/node.
// ---------------------------------------------------------------------------
__global__ __launch_bounds__(256) void k_att(
    const unsigned* __restrict__ xb, const float* __restrict__ att_src,
    const float* __restrict__ att_dst, float* __restrict__ a_src,
    float* __restrict__ a_dst, int N)
{
    int t = threadIdx.x;
    int node = blockIdx.x * 16 + (t >> 4);
    int lane = t & 15;
    if (node >= N) return;
    const uint4* x4 = (const uint4*)xb;
    uint4 xv = x4[(size_t)node * 16 + lane];
    int c = lane * 8;
    float xs[8];
    xs[0] = __uint_as_float(xv.x << 16); xs[1] = __uint_as_float(xv.x & 0xffff0000u);
    xs[2] = __uint_as_float(xv.y << 16); xs[3] = __uint_as_float(xv.y & 0xffff0000u);
    xs[4] = __uint_as_float(xv.z << 16); xs[5] = __uint_as_float(xv.z & 0xffff0000u);
    xs[6] = __uint_as_float(xv.w << 16); xs[7] = __uint_as_float(xv.w & 0xffff0000u);
    float ps = 0.f, pd = 0.f;
    #pragma unroll
    for (int i = 0; i < 8; ++i) {
        ps += xs[i] * att_src[c + i];
        pd += xs[i] * att_dst[c + i];
    }
    ps += __shfl_xor(ps, 1); ps += __shfl_xor(ps, 2);
    pd += __shfl_xor(pd, 1); pd += __shfl_xor(pd, 2);
    if ((lane & 3) == 0) {
        a_src[node * 4 + (lane >> 2)] = ps;
        a_dst[node * 4 + (lane >> 2)] = pd;
    }
}

// ---------------------------------------------------------------------------
// K3: fused pull over slots, 2-deep pipeline + batched x-row gathers.
// 16 lanes/node; logit finish + softmax + weighted sum + bias + LN + LeakyReLU.
// ---------------------------------------------------------------------------
__global__ __launch_bounds__(256) void k_agg(
    const int* __restrict__ cnt, const int4* __restrict__ slots,
    const float* __restrict__ a_src, const float* __restrict__ a_dst,
    const unsigned* __restrict__ xb, const float* __restrict__ bias,
    const float* __restrict__ gamma, const float* __restrict__ beta,
    float* __restrict__ out, int N)
{
    int t = threadIdx.x;
    int node = blockIdx.x * 16 + (t >> 4);
    int lane = t & 15;
    if (node >= N) return;
    int st = node * CAP;
    int deg = cnt[node]; if (deg > CAP) deg = CAP;
    int en = st + deg;
    int hsel = lane >> 2;
    float adst = a_dst[node * 4 + hsel];
    const uint4* x4 = (const uint4*)xb;
    float acc[8] = {0.f, 0.f, 0.f, 0.f, 0.f, 0.f, 0.f, 0.f};
    float denom = 0.f;

    int   s0[4], s1[4], s2[4];
    float ae0[4], ae1[4], ae2[4];
    float as0[4], as1[4];

    #define LOADG(P, S, AE)                                                   \
        {                                                                     \
            _Pragma("unroll")                                                 \
            for (int j = 0; j < 4; ++j) {                                     \
                bool v = ((P) + j) < en;                                      \
                int a = v ? ((P) + j) : st;                                   \
                int4 pk = slots[a];                                           \
                (S)[j] = pk.x;                                                \
                unsigned w = (hsel & 2) ? (unsigned)pk.z : (unsigned)pk.y;    \
                float e = __uint_as_float((hsel & 1) ? (w & 0xffff0000u)      \
                                                     : (w << 16));            \
                (AE)[j] = v ? e : -1e30f;                                     \
            }                                                                 \
        }
    #define GATHA(S, AS)                                                      \
        {                                                                     \
            _Pragma("unroll")                                                 \
            for (int j = 0; j < 4; ++j) (AS)[j] = a_src[(S)[j] * 4 + hsel];   \
        }

    if (st < en) {
        LOADG(st, s0, ae0);
        LOADG(st + 4, s1, ae1);
        GATHA(s0, as0);

        for (int p = st; p < en; p += 4) {
            GATHA(s1, as1);           // a_src for next group
            LOADG(p + 8, s2, ae2);    // slots two groups ahead

            // batch-issue the 4 independent x-row gathers
            uint4 xv[4];
            #pragma unroll
            for (int j = 0; j < 4; ++j)
                xv[j] = x4[(size_t)s0[j] * 16 + lane];

            #pragma unroll
            for (int j = 0; j < 4; ++j) {
                float al = as0[j] + adst + ae0[j];
                al = (al < 0.f) ? 0.2f * al : al;
                float ex = __expf(al);
                denom += ex;
                acc[0] += ex * __uint_as_float(xv[j].x << 16);
                acc[1] += ex * __uint_as_float(xv[j].x & 0xffff0000u);
                acc[2] += ex * __uint_as_float(xv[j].y << 16);
                acc[3] += ex * __uint_as_float(xv[j].y & 0xffff0000u);
                acc[4] += ex * __uint_as_float(xv[j].z << 16);
                acc[5] += ex * __uint_as_float(xv[j].z & 0xffff0000u);
                acc[6] += ex * __uint_as_float(xv[j].w << 16);
                acc[7] += ex * __uint_as_float(xv[j].w & 0xffff0000u);
            }
            #pragma unroll
            for (int j = 0; j < 4; ++j) {
                s0[j] = s1[j]; ae0[j] = ae1[j]; as0[j] = as1[j];
                s1[j] = s2[j]; ae1[j] = ae2[j];
            }
        }
    }
    #undef LOADG
    #undef GATHA

    float inv = 1.f / (denom + 1e-16f);
    int c = lane * 8;
    float4 b0 = *(const float4*)&bias[c];
    float4 b1 = *(const float4*)&bias[c + 4];
    float o[8];
    o[0] = acc[0] * inv + b0.x; o[1] = acc[1] * inv + b0.y;
    o[2] = acc[2] * inv + b0.z; o[3] = acc[3] * inv + b0.w;
    o[4] = acc[4] * inv + b1.x; o[5] = acc[5] * inv + b1.y;
    o[6] = acc[6] * inv + b1.z; o[7] = acc[7] * inv + b1.w;

    float s = 0.f;
    #pragma unroll
    for (int i = 0; i < 8; ++i) s += o[i];
    #pragma unroll
    for (int m = 1; m < 16; m <<= 1) s += __shfl_xor(s, m, 16);
    float mu = s * (1.0f / 128.0f);
    float q = 0.f;
    #pragma unroll
    for (int i = 0; i < 8; ++i) { o[i] -= mu; q += o[i] * o[i]; }
    #pragma unroll
    for (int m = 1; m < 16; m <<= 1) q += __shfl_xor(q, m, 16);
    float rstd = rsqrtf(q * (1.0f / 128.0f) + 1e-5f);
    float4 g0 = *(const float4*)&gamma[c];
    float4 g1 = *(const float4*)&gamma[c + 4];
    float4 e0 = *(const float4*)&beta[c];
    float4 e1 = *(const float4*)&beta[c + 4];
    float y[8];
    y[0] = o[0] * rstd * g0.x + e0.x; y[1] = o[1] * rstd * g0.y + e0.y;
    y[2] = o[2] * rstd * g0.z + e0.z; y[3] = o[3] * rstd * g0.w + e0.w;
    y[4] = o[4] * rstd * g1.x + e1.x; y[5] = o[5] * rstd * g1.y + e1.y;
    y[6] = o[6] * rstd * g1.z + e1.z; y[7] = o[7] * rstd * g1.w + e1.w;
    #pragma unroll
    for (int i = 0; i < 8; ++i) y[i] = (y[i] < 0.f) ? 0.01f * y[i] : y[i];
    float4 r0 = {y[0], y[1], y[2], y[3]};
    float4 r1 = {y[4], y[5], y[6], y[7]};
    float4* op = (float4*)out + (size_t)node * 32 + lane * 2;
    op[0] = r0;
    op[1] = r1;
}

// ---------------------------------------------------------------------------
extern "C" void kernel_launch(void* const* d_in, const int* in_sizes, int n_in,
                              void* d_out, int out_size, void* d_ws, size_t ws_size,
                              hipStream_t stream) {
    const float* point_attr = (const float*)d_in[0];
    const int*   edge_index = (const int*)d_in[1];
    const float* edge_attr  = (const float*)d_in[2];
    const float* W          = (const float*)d_in[3];
    const float* att_src    = (const float*)d_in[4];
    const float* att_dst    = (const float*)d_in[5];
    const float* W_edge     = (const float*)d_in[6];
    const float* att_edge   = (const float*)d_in[7];
    const float* bias       = (const float*)d_in[8];
    const float* ln_gamma   = (const float*)d_in[9];
    const float* ln_beta    = (const float*)d_in[10];

    int N = in_sizes[0] / IN_DIM;
    int E = in_sizes[2] / EDGE_DIM;
    float* out = (float*)d_out;

    char* ws = (char*)d_ws;
    size_t off = 0;
    auto alloc = [&](size_t bytes) {
        void* p = ws + off;
        off += (bytes + 255) & ~(size_t)255;
        return p;
    };
    unsigned* xb     = (unsigned*)alloc((size_t)N * 128 * 2);   // bf16 x (25.6MB)
    float* a_src     = (float*)alloc((size_t)N * 4 * 4);
    float* a_dst     = (float*)alloc((size_t)N * 4 * 4);
    int*   cnt       = (int*)alloc((size_t)N * 4);
    float* v_edge    = (float*)alloc(128 * 4);
    unsigned short* Wt = (unsigned short*)alloc(128 * 128 * 2);
    int4*  slots     = (int4*)alloc((size_t)N * CAP * 16);      // 76.8MB

    hipMemsetAsync(cnt, 0, (size_t)N * 4, stream);

    int nbEdge = (E + 255) / 256;
    int nbGemm = (N + 63) / 64;
    int nbAtt  = (N + 15) / 16;

    k_vp<<<65, 256, 0, stream>>>(W_edge, att_edge, v_edge, W, Wt);
    // single fused pass: edge dot + direct slot scatter  ||  gemm
    k_phase1<<<nbEdge + nbGemm, 256, 0, stream>>>(
        edge_attr, edge_index, v_edge, cnt, slots,
        point_attr, Wt, (unsigned short*)xb, N, E, nbEdge);
    k_att<<<nbAtt, 256, 0, stream>>>(xb, att_src, att_dst, a_src, a_dst, N);
    k_agg<<<nbAtt, 256, 0, stream>>>(cnt, slots, a_src, a_dst, xb,
                                     bias, ln_gamma, ln_beta, out, N);
}

// Round 19
// 239.241 us; speedup vs baseline: 1.0347x; 1.0347x over previous
//
#include <hip/hip_runtime.h>
#include <hip/hip_bf16.h>

#define IN_DIM 128
#define HC 128   // H*C
#define NH 4     // heads
#define CH 32    // channels per head
#define EDGE_DIM 32
#define CAP 48   // slots per dst; degree ~ Poisson(16), P(deg>48) ~ 1e-10

typedef short s8v __attribute__((ext_vector_type(8)));   // 8 bf16 (4 VGPR)
typedef float f4v __attribute__((ext_vector_type(4)));   // mfma acc

// ---------------------------------------------------------------------------
__device__ __forceinline__ unsigned pack_bf16(float a, float b) {
    unsigned ua = __float_as_uint(a), ub = __float_as_uint(b);
    ua += 0x7fffu + ((ua >> 16) & 1u);
    ub += 0x7fffu + ((ub >> 16) & 1u);
    return (ua >> 16) | (ub & 0xffff0000u);
}
__device__ __forceinline__ unsigned short bf16_1(float a) {
    unsigned ua = __float_as_uint(a);
    ua += 0x7fffu + ((ua >> 16) & 1u);
    return (unsigned short)(ua >> 16);
}

// ---------------------------------------------------------------------------
// K0: fused tiny prep: blocks 0..63 -> Wt[n][k]=bf16(W[k][n]); block 64 -> v_edge
// ---------------------------------------------------------------------------
__global__ __launch_bounds__(256) void k_vp(
    const float* __restrict__ W_edge, const float* __restrict__ att_edge,
    float* __restrict__ v_edge, const float* __restrict__ W,
    unsigned short* __restrict__ Wt)
{
    int b = blockIdx.x, t = threadIdx.x;
    if (b == 64) {
        if (t < 128) {
            int h = t >> 5, k = t & 31;
            float s = 0.f;
            #pragma unroll
            for (int c = 0; c < CH; ++c)
                s += W_edge[k * HC + h * CH + c] * att_edge[h * CH + c];
            v_edge[h * EDGE_DIM + k] = s;
        }
    } else {
        int id = b * 256 + t;
        int n = id >> 7, k = id & 127;
        Wt[n * 128 + k] = bf16_1(W[k * 128 + n]);
    }
}

// ---------------------------------------------------------------------------
// K1 (fused single pass): blocks [0,nbEdge): 512 edges/block, 2 edges/thread
// (two independent dot+atomic+store chains -> 2x memory-level parallelism on
// the scatter path). blocks [nbEdge,...): x = A@W via bf16 MFMA.
// ---------------------------------------------------------------------------
__global__ __launch_bounds__(256) void k_phase1(
    const float* __restrict__ edge_attr, const int* __restrict__ ei,
    const float* __restrict__ v_edge, int* __restrict__ cnt,
    int4* __restrict__ slots,
    const float* __restrict__ A, const unsigned short* __restrict__ Wt,
    unsigned short* __restrict__ xb16, int N, int E, int nbEdge)
{
    __shared__ unsigned Al[64 * 64];   // gemm A tile (16 KB)
    __shared__ float vl[HC];           // edge path v_edge

    int t = threadIdx.x;

    if (blockIdx.x < nbEdge) {
        if (t < HC) vl[t] = v_edge[t];
        __syncthreads();
        int base = blockIdx.x * 512;

        #pragma unroll
        for (int ee = 0; ee < 2; ++ee) {
            int e = base + ee * 256 + t;
            if (e >= E) continue;
            const float4* ea4 = (const float4*)edge_attr + (size_t)e * 8;
            float ae[4] = {0.f, 0.f, 0.f, 0.f};
            #pragma unroll
            for (int j = 0; j < 8; ++j) {
                float4 v = ea4[j];
                #pragma unroll
                for (int h = 0; h < 4; ++h) {
                    const float* vh = &vl[h * 32 + j * 4];
                    ae[h] += v.x * vh[0] + v.y * vh[1] + v.z * vh[2] + v.w * vh[3];
                }
            }
            int src = ei[e], dst = ei[E + e];
            int pos = atomicAdd(&cnt[dst], 1);
            if (pos < CAP) {
                int4 pk;
                pk.x = src;
                pk.y = (int)pack_bf16(ae[0], ae[1]);
                pk.z = (int)pack_bf16(ae[2], ae[3]);
                pk.w = 0;
                slots[(size_t)dst * CAP + pos] = pk;
            }
        }
    } else {
        int node0 = (blockIdx.x - nbEdge) * 64;
        const float4* A4 = (const float4*)A;
        #pragma unroll
        for (int it = 0; it < 8; ++it) {
            int id = it * 256 + t;
            int row = id >> 5, c = id & 31;
            float4 v = {0.f, 0.f, 0.f, 0.f};
            if (node0 + row < N) v = A4[(size_t)(node0 + row) * 32 + c];
            unsigned u0 = pack_bf16(v.x, v.y);
            unsigned u1 = pack_bf16(v.z, v.w);
            int k2 = 2 * c;
            int slot = k2 >> 2;
            int idx = ((slot ^ (row & 15)) << 2) | (k2 & 3);
            Al[row * 64 + idx]     = u0;
            Al[row * 64 + idx + 1] = u1;
        }
        __syncthreads();

        int l = t & 63;
        int w = t >> 6;
        int lrow = l & 15;
        int lk   = l >> 4;

        s8v afr[4];
        #pragma unroll
        for (int kb = 0; kb < 4; ++kb) {
            int slot = kb * 4 + lk;
            const unsigned* p = &Al[(w * 16 + lrow) * 64 + ((slot ^ lrow) << 2)];
            afr[kb] = *(const s8v*)p;
        }

        #pragma unroll
        for (int ct = 0; ct < 8; ++ct) {
            int col = ct * 16 + lrow;
            f4v acc = {0.f, 0.f, 0.f, 0.f};
            #pragma unroll
            for (int kb = 0; kb < 4; ++kb) {
                s8v bfr = *(const s8v*)&Wt[col * 128 + kb * 32 + lk * 8];
                acc = __builtin_amdgcn_mfma_f32_16x16x32_bf16(afr[kb], bfr, acc, 0, 0, 0);
            }
            #pragma unroll
            for (int r = 0; r < 4; ++r) {
                int node = node0 + w * 16 + lk * 4 + r;
                if (node < N) xb16[(size_t)node * 128 + col] = bf16_1(acc[r]);
            }
        }
    }
}

// ---------------------------------------------------------------------------
// K2: a_src/a_dst from bf16 x. 16 lanes/node.
// ---------------------------------------------------------------------------
__global__ __launch_bounds__(256) void k_att(
    const unsigned* __restrict__ xb, const float* __restrict__ att_src,
    const float* __restrict__ att_dst, float* __restrict__ a_src,
    float* __restrict__ a_dst, int N)
{
    int t = threadIdx.x;
    int node = blockIdx.x * 16 + (t >> 4);
    int lane = t & 15;
    if (node >= N) return;
    const uint4* x4 = (const uint4*)xb;
    uint4 xv = x4[(size_t)node * 16 + lane];
    int c = lane * 8;
    float xs[8];
    xs[0] = __uint_as_float(xv.x << 16); xs[1] = __uint_as_float(xv.x & 0xffff0000u);
    xs[2] = __uint_as_float(xv.y << 16); xs[3] = __uint_as_float(xv.y & 0xffff0000u);
    xs[4] = __uint_as_float(xv.z << 16); xs[5] = __uint_as_float(xv.z & 0xffff0000u);
    xs[6] = __uint_as_float(xv.w << 16); xs[7] = __uint_as_float(xv.w & 0xffff0000u);
    float ps = 0.f, pd = 0.f;
    #pragma unroll
    for (int i = 0; i < 8; ++i) {
        ps += xs[i] * att_src[c + i];
        pd += xs[i] * att_dst[c + i];
    }
    ps += __shfl_xor(ps, 1); ps += __shfl_xor(ps, 2);
    pd += __shfl_xor(pd, 1); pd += __shfl_xor(pd, 2);
    if ((lane & 3) == 0) {
        a_src[node * 4 + (lane >> 2)] = ps;
        a_dst[node * 4 + (lane >> 2)] = pd;
    }
}

// ---------------------------------------------------------------------------
// K3: fused pull over slots, 2-deep software pipeline (R17 winner).
// 16 lanes/node; logit finish + softmax + weighted sum + bias + LN + LeakyReLU.
// ---------------------------------------------------------------------------
__global__ __launch_bounds__(256) void k_agg(
    const int* __restrict__ cnt, const int4* __restrict__ slots,
    const float* __restrict__ a_src, const float* __restrict__ a_dst,
    const unsigned* __restrict__ xb, const float* __restrict__ bias,
    const float* __restrict__ gamma, const float* __restrict__ beta,
    float* __restrict__ out, int N)
{
    int t = threadIdx.x;
    int node = blockIdx.x * 16 + (t >> 4);
    int lane = t & 15;
    if (node >= N) return;
    int st = node * CAP;
    int deg = cnt[node]; if (deg > CAP) deg = CAP;
    int en = st + deg;
    int hsel = lane >> 2;
    float adst = a_dst[node * 4 + hsel];
    const uint4* x4 = (const uint4*)xb;
    float acc[8] = {0.f, 0.f, 0.f, 0.f, 0.f, 0.f, 0.f, 0.f};
    float denom = 0.f;

    int   s0[4], s1[4], s2[4];
    float ae0[4], ae1[4], ae2[4];
    float as0[4], as1[4];

    #define LOADG(P, S, AE)                                                   \
        {                                                                     \
            _Pragma("unroll")                                                 \
            for (int j = 0; j < 4; ++j) {                                     \
                bool v = ((P) + j) < en;                                      \
                int a = v ? ((P) + j) : st;                                   \
                int4 pk = slots[a];                                           \
                (S)[j] = pk.x;                                                \
                unsigned w = (hsel & 2) ? (unsigned)pk.z : (unsigned)pk.y;    \
                float e = __uint_as_float((hsel & 1) ? (w & 0xffff0000u)      \
                                                     : (w << 16));            \
                (AE)[j] = v ? e : -1e30f;                                     \
            }                                                                 \
        }
    #define GATHA(S, AS)                                                      \
        {                                                                     \
            _Pragma("unroll")                                                 \
            for (int j = 0; j < 4; ++j) (AS)[j] = a_src[(S)[j] * 4 + hsel];   \
        }

    if (st < en) {
        LOADG(st, s0, ae0);
        LOADG(st + 4, s1, ae1);
        GATHA(s0, as0);

        for (int p = st; p < en; p += 4) {
            GATHA(s1, as1);           // a_src for next group
            LOADG(p + 8, s2, ae2);    // slots two groups ahead

            #pragma unroll
            for (int j = 0; j < 4; ++j) {
                float al = as0[j] + adst + ae0[j];
                al = (al < 0.f) ? 0.2f * al : al;
                float ex = __expf(al);
                denom += ex;
                uint4 xv = x4[(size_t)s0[j] * 16 + lane];
                acc[0] += ex * __uint_as_float(xv.x << 16);
                acc[1] += ex * __uint_as_float(xv.x & 0xffff0000u);
                acc[2] += ex * __uint_as_float(xv.y << 16);
                acc[3] += ex * __uint_as_float(xv.y & 0xffff0000u);
                acc[4] += ex * __uint_as_float(xv.z << 16);
                acc[5] += ex * __uint_as_float(xv.z & 0xffff0000u);
                acc[6] += ex * __uint_as_float(xv.w << 16);
                acc[7] += ex * __uint_as_float(xv.w & 0xffff0000u);
            }
            #pragma unroll
            for (int j = 0; j < 4; ++j) {
                s0[j] = s1[j]; ae0[j] = ae1[j]; as0[j] = as1[j];
                s1[j] = s2[j]; ae1[j] = ae2[j];
            }
        }
    }
    #undef LOADG
    #undef GATHA

    float inv = 1.f / (denom + 1e-16f);
    int c = lane * 8;
    float4 b0 = *(const float4*)&bias[c];
    float4 b1 = *(const float4*)&bias[c + 4];
    float o[8];
    o[0] = acc[0] * inv + b0.x; o[1] = acc[1] * inv + b0.y;
    o[2] = acc[2] * inv + b0.z; o[3] = acc[3] * inv + b0.w;
    o[4] = acc[4] * inv + b1.x; o[5] = acc[5] * inv + b1.y;
    o[6] = acc[6] * inv + b1.z; o[7] = acc[7] * inv + b1.w;

    float s = 0.f;
    #pragma unroll
    for (int i = 0; i < 8; ++i) s += o[i];
    #pragma unroll
    for (int m = 1; m < 16; m <<= 1) s += __shfl_xor(s, m, 16);
    float mu = s * (1.0f / 128.0f);
    float q = 0.f;
    #pragma unroll
    for (int i = 0; i < 8; ++i) { o[i] -= mu; q += o[i] * o[i]; }
    #pragma unroll
    for (int m = 1; m < 16; m <<= 1) q += __shfl_xor(q, m, 16);
    float rstd = rsqrtf(q * (1.0f / 128.0f) + 1e-5f);
    float4 g0 = *(const float4*)&gamma[c];
    float4 g1 = *(const float4*)&gamma[c + 4];
    float4 e0 = *(const float4*)&beta[c];
    float4 e1 = *(const float4*)&beta[c + 4];
    float y[8];
    y[0] = o[0] * rstd * g0.x + e0.x; y[1] = o[1] * rstd * g0.y + e0.y;
    y[2] = o[2] * rstd * g0.z + e0.z; y[3] = o[3] * rstd * g0.w + e0.w;
    y[4] = o[4] * rstd * g1.x + e1.x; y[5] = o[5] * rstd * g1.y + e1.y;
    y[6] = o[6] * rstd * g1.z + e1.z; y[7] = o[7] * rstd * g1.w + e1.w;
    #pragma unroll
    for (int i = 0; i < 8; ++i) y[i] = (y[i] < 0.f) ? 0.01f * y[i] : y[i];
    float4 r0 = {y[0], y[1], y[2], y[3]};
    float4 r1 = {y[4], y[5], y[6], y[7]};
    float4* op = (float4*)out + (size_t)node * 32 + lane * 2;
    op[0] = r0;
    op[1] = r1;
}

// ---------------------------------------------------------------------------
extern "C" void kernel_launch(void* const* d_in, const int* in_sizes, int n_in,
                              void* d_out, int out_size, void* d_ws, size_t ws_size,
                              hipStream_t stream) {
    const float* point_attr = (const float*)d_in[0];
    const int*   edge_index = (const int*)d_in[1];
    const float* edge_attr  = (const float*)d_in[2];
    const float* W          = (const float*)d_in[3];
    const float* att_src    = (const float*)d_in[4];
    const float* att_dst    = (const float*)d_in[5];
    const float* W_edge     = (const float*)d_in[6];
    const float* att_edge   = (const float*)d_in[7];
    const float* bias       = (const float*)d_in[8];
    const float* ln_gamma   = (const float*)d_in[9];
    const float* ln_beta    = (const float*)d_in[10];

    int N = in_sizes[0] / IN_DIM;
    int E = in_sizes[2] / EDGE_DIM;
    float* out = (float*)d_out;

    char* ws = (char*)d_ws;
    size_t off = 0;
    auto alloc = [&](size_t bytes) {
        void* p = ws + off;
        off += (bytes + 255) & ~(size_t)255;
        return p;
    };
    unsigned* xb     = (unsigned*)alloc((size_t)N * 128 * 2);   // bf16 x (25.6MB)
    float* a_src     = (float*)alloc((size_t)N * 4 * 4);
    float* a_dst     = (float*)alloc((size_t)N * 4 * 4);
    int*   cnt       = (int*)alloc((size_t)N * 4);
    float* v_edge    = (float*)alloc(128 * 4);
    unsigned short* Wt = (unsigned short*)alloc(128 * 128 * 2);
    int4*  slots     = (int4*)alloc((size_t)N * CAP * 16);      // 76.8MB

    hipMemsetAsync(cnt, 0, (size_t)N * 4, stream);

    int nbEdge = (E + 511) / 512;
    int nbGemm = (N + 63) / 64;
    int nbAtt  = (N + 15) / 16;

    k_vp<<<65, 256, 0, stream>>>(W_edge, att_edge, v_edge, W, Wt);
    // single fused pass: edge dot + direct slot scatter (2 edges/thread) || gemm
    k_phase1<<<nbEdge + nbGemm, 256, 0, stream>>>(
        edge_attr, edge_index, v_edge, cnt, slots,
        point_attr, Wt, (unsigned short*)xb, N, E, nbEdge);
    k_att<<<nbAtt, 256, 0, stream>>>(xb, att_src, att_dst, a_src, a_dst, N);
    k_agg<<<nbAtt, 256, 0, stream>>>(cnt, slots, a_src, a_dst, xb,
                                     bias, ln_gamma, ln_beta, out, N);
}